// Round 1
// baseline (232.038 us; speedup 1.0000x reference)
//
#include <hip/hip_runtime.h>

// EdgeConv on dense bipartite graph: A=256, U=1024, D=64.
// out[a,u] = edge@W3t - (relu(edge@W1b+c1[a]) + relu(edge@W2b+c2[u]))@W3b + s3[a] + s4[u]
// with c1 = ap_hid@W1t+b1, c2 = ue_hid@W2t+b2, s3 = ap_sum@W3b, s4 = ue_sum@W3b+b3.

#define A_N 256
#define U_N 1024
#define D_N 64

typedef short short8 __attribute__((ext_vector_type(8)));
typedef float f32x4 __attribute__((ext_vector_type(4)));

__device__ __forceinline__ unsigned short f2bf(float f) {
  unsigned int u = __float_as_uint(f);
  unsigned int r = (u + 0x7FFFu + ((u >> 16) & 1u)) >> 16;  // RNE
  return (unsigned short)r;
}

__device__ __forceinline__ f32x4 mfma16(short8 a, short8 b, f32x4 c) {
  return __builtin_amdgcn_mfma_f32_16x16x32_bf16(a, b, c, 0, 0, 0);
}

__global__ __launch_bounds__(256) void k_zero(float* __restrict__ p, int n) {
  int i = blockIdx.x * 256 + threadIdx.x;
  if (i < n) p[i] = 0.f;
}

// Wt rows 0-63: W1_bot^T (n-major), 64-127: W2_bot^T, 128-191: W3_top^T, 192-255: W3_bot^T
__global__ __launch_bounds__(256) void k_setup_weights(
    const float* __restrict__ W1, const float* __restrict__ W2,
    const float* __restrict__ W3, unsigned short* __restrict__ Wt) {
  int idx = blockIdx.x * 256 + threadIdx.x;  // 16384 total
  int r = idx >> 6, k = idx & 63;
  int sec = r >> 6, d = r & 63;
  float v;
  if (sec == 0)      v = W1[(64 + k) * 64 + d];
  else if (sec == 1) v = W2[(64 + k) * 64 + d];
  else if (sec == 2) v = W3[k * 64 + d];
  else               v = W3[(64 + k) * 64 + d];
  Wt[r * 64 + k] = f2bf(v);
}

// out[r][d] = sum_k in[r][k] * W[k*64+d] (+ bias[d]); one row per 64-thread block.
__global__ __launch_bounds__(64) void k_rowmlp(
    const float* __restrict__ in, const float* __restrict__ W,
    const float* __restrict__ bias, float* __restrict__ out) {
  int r = blockIdx.x, lane = threadIdx.x;
  float rv = in[r * 64 + lane];
  float acc = bias ? bias[lane] : 0.f;
  float wv[64];
#pragma unroll
  for (int k = 0; k < 64; k++) wv[k] = W[k * 64 + lane];
#pragma unroll
  for (int k = 0; k < 64; k++) acc += __shfl(rv, k, 64) * wv[k];
  out[r * 64 + lane] = acc;
}

// Pass 1: ap_sum[a] = sum_u relu(edge@W1b + c1[a]); ue_sum[u] = sum_a relu(edge@W2b + c2[u]).
// Block = 8 a's x 64 u's; each wave owns a 16-u panel -> no __syncthreads needed
// (staging rows, frag rows all wave-private; DS ops are in-order per wave).
__global__ __launch_bounds__(256) void k_pass1(
    const float* __restrict__ edge, const unsigned short* __restrict__ Wt,
    const float* __restrict__ c1, const float* __restrict__ c2,
    float* __restrict__ ap_sum, float* __restrict__ ue_sum) {
  __shared__ unsigned short E_lds[64 * 72];  // 64 rows (u), stride 72 bf16
  int tid = threadIdx.x, lane = tid & 63, w = tid >> 6;
  int fr = lane & 15, fq = lane >> 4;
  int bx = blockIdx.x;
  int a0 = (bx >> 4) * 8, u0 = (bx & 15) * 64;

  // loop-invariant B-fragments: n-tiles 0-3 = W1b, 4-7 = W2b
  short8 bw[8][2];
#pragma unroll
  for (int nt = 0; nt < 8; nt++)
#pragma unroll
    for (int ks = 0; ks < 2; ks++)
      bw[nt][ks] = *(const short8*)(Wt + (nt * 16 + fr) * 64 + ks * 32 + fq * 8);

  // loop-invariant c2 gather (u fixed per lane/reg across chunks)
  float c2v[4][4];
#pragma unroll
  for (int j = 0; j < 4; j++)
#pragma unroll
    for (int i = 0; i < 4; i++)
      c2v[j][i] = c2[(u0 + w * 16 + fq * 4 + i) * 64 + j * 16 + fr];

  float ureg[4][4];
#pragma unroll
  for (int j = 0; j < 4; j++)
#pragma unroll
    for (int i = 0; i < 4; i++) ureg[j][i] = 0.f;

  int srow = tid >> 2, scg = (tid & 3) * 16;  // wave w stages exactly rows 16w..16w+15
  unsigned short* stp = &E_lds[srow * 72 + scg];

  for (int c = 0; c < 8; c++) {
    int a = a0 + c;
    const float4* src = (const float4*)(edge + (a * 1024 + u0 + srow) * 64 + scg);
    float4 f0 = src[0], f1 = src[1], f2 = src[2], f3 = src[3];
    float ft[16] = {f0.x, f0.y, f0.z, f0.w, f1.x, f1.y, f1.z, f1.w,
                    f2.x, f2.y, f2.z, f2.w, f3.x, f3.y, f3.z, f3.w};
    short8 p0, p1;
#pragma unroll
    for (int i = 0; i < 8; i++) {
      p0[i] = (short)f2bf(ft[i]);
      p1[i] = (short)f2bf(ft[8 + i]);
    }
    *(short8*)stp = p0;
    *(short8*)(stp + 8) = p1;

    // A-fragments from this wave's own rows
    short8 af0 = *(const short8*)&E_lds[(w * 16 + fr) * 72 + fq * 8];
    short8 af1 = *(const short8*)&E_lds[(w * 16 + fr) * 72 + 32 + fq * 8];

    // P1 -> reduce over the wave's 16 u-rows -> ap_sum[a]
#pragma unroll
    for (int j = 0; j < 4; j++) {
      f32x4 acc = {0.f, 0.f, 0.f, 0.f};
      acc = mfma16(af0, bw[j][0], acc);
      acc = mfma16(af1, bw[j][1], acc);
      float c1v = c1[a * 64 + j * 16 + fr];
      float rs = fmaxf(acc[0] + c1v, 0.f) + fmaxf(acc[1] + c1v, 0.f) +
                 fmaxf(acc[2] + c1v, 0.f) + fmaxf(acc[3] + c1v, 0.f);
      rs += __shfl_xor(rs, 16, 64);
      rs += __shfl_xor(rs, 32, 64);
      if (lane < 16) atomicAdd(&ap_sum[a * 64 + j * 16 + lane], rs);
    }
    // P2 -> per-(u,d) register accumulation across the 8 a's
#pragma unroll
    for (int j = 0; j < 4; j++) {
      f32x4 acc = {0.f, 0.f, 0.f, 0.f};
      acc = mfma16(af0, bw[4 + j][0], acc);
      acc = mfma16(af1, bw[4 + j][1], acc);
#pragma unroll
      for (int i = 0; i < 4; i++)
        ureg[j][i] += fmaxf(acc[i] + c2v[j][i], 0.f);
    }
  }
#pragma unroll
  for (int j = 0; j < 4; j++)
#pragma unroll
    for (int i = 0; i < 4; i++)
      atomicAdd(&ue_sum[(u0 + w * 16 + fq * 4 + i) * 64 + j * 16 + fr], ureg[j][i]);
}

// Pass 2: out = P3 - t@W3b + s3[a] + s4[u], t = relu(P1+c1)+relu(P2+c2), P* = edge@{W1b,W2b,W3t}.
// Block = (one a) x 64 u's, wave-private 16-u panels, t round-trips through LDS (C-layout -> A-layout).
__global__ __launch_bounds__(256) void k_pass2(
    const float* __restrict__ edge, const unsigned short* __restrict__ Wt,
    const float* __restrict__ c1, const float* __restrict__ c2,
    const float* __restrict__ s3, const float* __restrict__ s4,
    float* __restrict__ out) {
  __shared__ unsigned short E_lds[64 * 72];
  __shared__ unsigned short t_lds[64 * 72];
  int tid = threadIdx.x, lane = tid & 63, w = tid >> 6;
  int fr = lane & 15, fq = lane >> 4;
  int bx = blockIdx.x;
  int a = bx >> 4, u0 = (bx & 15) * 64;

  int srow = tid >> 2, scg = (tid & 3) * 16;
  {
    const float4* src = (const float4*)(edge + (a * 1024 + u0 + srow) * 64 + scg);
    float4 f0 = src[0], f1 = src[1], f2 = src[2], f3 = src[3];
    float ft[16] = {f0.x, f0.y, f0.z, f0.w, f1.x, f1.y, f1.z, f1.w,
                    f2.x, f2.y, f2.z, f2.w, f3.x, f3.y, f3.z, f3.w};
    short8 p0, p1;
#pragma unroll
    for (int i = 0; i < 8; i++) {
      p0[i] = (short)f2bf(ft[i]);
      p1[i] = (short)f2bf(ft[8 + i]);
    }
    *(short8*)&E_lds[srow * 72 + scg] = p0;
    *(short8*)&E_lds[srow * 72 + scg + 8] = p1;
  }
  short8 af0 = *(const short8*)&E_lds[(w * 16 + fr) * 72 + fq * 8];
  short8 af1 = *(const short8*)&E_lds[(w * 16 + fr) * 72 + 32 + fq * 8];

  f32x4 accP3[4];
#pragma unroll
  for (int j = 0; j < 4; j++) {
    short8 b10 = *(const short8*)(Wt + (j * 16 + fr) * 64 + fq * 8);
    short8 b11 = *(const short8*)(Wt + (j * 16 + fr) * 64 + 32 + fq * 8);
    f32x4 a1 = {0.f, 0.f, 0.f, 0.f};
    a1 = mfma16(af0, b10, a1);
    a1 = mfma16(af1, b11, a1);
    short8 b20 = *(const short8*)(Wt + (64 + j * 16 + fr) * 64 + fq * 8);
    short8 b21 = *(const short8*)(Wt + (64 + j * 16 + fr) * 64 + 32 + fq * 8);
    f32x4 a2 = {0.f, 0.f, 0.f, 0.f};
    a2 = mfma16(af0, b20, a2);
    a2 = mfma16(af1, b21, a2);
    short8 b30 = *(const short8*)(Wt + (128 + j * 16 + fr) * 64 + fq * 8);
    short8 b31 = *(const short8*)(Wt + (128 + j * 16 + fr) * 64 + 32 + fq * 8);
    f32x4 p3 = {0.f, 0.f, 0.f, 0.f};
    p3 = mfma16(af0, b30, p3);
    p3 = mfma16(af1, b31, p3);
    accP3[j] = p3;
    float c1v = c1[a * 64 + j * 16 + fr];
#pragma unroll
    for (int i = 0; i < 4; i++) {
      int urow = w * 16 + fq * 4 + i;
      float c2vv = c2[(u0 + urow) * 64 + j * 16 + fr];
      float tv = fmaxf(a1[i] + c1v, 0.f) + fmaxf(a2[i] + c2vv, 0.f);
      t_lds[urow * 72 + j * 16 + fr] = f2bf(tv);  // wave-private rows
    }
  }
  // GEMM2: A = t (this wave's rows) - DS in-order per wave, no barrier needed
  short8 tf0 = *(const short8*)&t_lds[(w * 16 + fr) * 72 + fq * 8];
  short8 tf1 = *(const short8*)&t_lds[(w * 16 + fr) * 72 + 32 + fq * 8];
#pragma unroll
  for (int j = 0; j < 4; j++) {
    short8 b0 = *(const short8*)(Wt + (192 + j * 16 + fr) * 64 + fq * 8);
    short8 b1 = *(const short8*)(Wt + (192 + j * 16 + fr) * 64 + 32 + fq * 8);
    f32x4 acc = {0.f, 0.f, 0.f, 0.f};
    acc = mfma16(tf0, b0, acc);
    acc = mfma16(tf1, b1, acc);
    float s3v = s3[a * 64 + j * 16 + fr];
#pragma unroll
    for (int i = 0; i < 4; i++) {
      int urow = w * 16 + fq * 4 + i;
      int u = u0 + urow;
      float val = accP3[j][i] - acc[i] + s3v + s4[u * 64 + j * 16 + fr];
      out[(a * 1024 + u) * 64 + j * 16 + fr] = val;
    }
  }
}

extern "C" void kernel_launch(void* const* d_in, const int* in_sizes, int n_in,
                              void* d_out, int out_size, void* d_ws, size_t ws_size,
                              hipStream_t stream) {
  const float* ap_hid = (const float*)d_in[0];
  const float* ue_hid = (const float*)d_in[1];
  const float* edge   = (const float*)d_in[2];
  const float* W1     = (const float*)d_in[3];
  const float* b1     = (const float*)d_in[4];
  const float* W2     = (const float*)d_in[5];
  const float* b2     = (const float*)d_in[6];
  const float* W3     = (const float*)d_in[7];
  const float* b3     = (const float*)d_in[8];
  float* out = (float*)d_out;

  char* ws = (char*)d_ws;
  unsigned short* Wt = (unsigned short*)ws;          //  32768 B
  float* c1     = (float*)(ws + 32768);              //  65536 B
  float* c2     = (float*)(ws + 98304);              // 262144 B
  float* ap_sum = (float*)(ws + 360448);             //  65536 B
  float* ue_sum = (float*)(ws + 425984);             // 262144 B
  float* s3     = (float*)(ws + 688128);             //  65536 B
  float* s4     = (float*)(ws + 753664);             // 262144 B

  // zero the atomic accumulators (ap_sum + ue_sum, contiguous 81920 floats)
  k_zero<<<(81920 + 255) / 256, 256, 0, stream>>>((float*)(ws + 360448), 81920);
  k_setup_weights<<<64, 256, 0, stream>>>(W1, W2, W3, Wt);
  k_rowmlp<<<A_N, 64, 0, stream>>>(ap_hid, W1, b1, c1);
  k_rowmlp<<<U_N, 64, 0, stream>>>(ue_hid, W2, b2, c2);
  k_pass1<<<512, 256, 0, stream>>>(edge, Wt, c1, c2, ap_sum, ue_sum);
  k_rowmlp<<<A_N, 64, 0, stream>>>(ap_sum, W3 + 64 * 64, nullptr, s3);
  k_rowmlp<<<U_N, 64, 0, stream>>>(ue_sum, W3 + 64 * 64, b3, s4);
  k_pass2<<<4096, 256, 0, stream>>>(edge, Wt, c1, c2, s3, s4, out);
}

// Round 2
// 176.617 us; speedup vs baseline: 1.3138x; 1.3138x over previous
//
#include <hip/hip_runtime.h>

// EdgeConv on dense bipartite graph: A=256, U=1024, D=64.
// out[a,u] = edge@W3t - (relu(edge@W1b+c1[a]) + relu(edge@W2b+c2[u]))@W3b + s3[a] + s4[u]
// with c1 = ap_hid@W1t+b1, c2 = ue_hid@W2t+b2, s3 = ap_sum@W3b, s4 = ue_sum@W3b+b3.
//
// R2: latency-bound fix. Edge A-fragments loaded DIRECTLY from global (no LDS
// staging round-trip), 4 slices/panels per block with register prefetch of the
// next slice, pass2 weights staged once into padded LDS, small kernels fused.

#define A_N 256
#define U_N 1024

typedef short short8 __attribute__((ext_vector_type(8)));
typedef float f32x4 __attribute__((ext_vector_type(4)));

__device__ __forceinline__ unsigned short f2bf(float f) {
  unsigned int u = __float_as_uint(f);
  return (unsigned short)((u + 0x7FFFu + ((u >> 16) & 1u)) >> 16);  // RNE
}

__device__ __forceinline__ f32x4 mfma16(short8 a, short8 b, f32x4 c) {
  return __builtin_amdgcn_mfma_f32_16x16x32_bf16(a, b, c, 0, 0, 0);
}

__device__ __forceinline__ void cvt16(const float4& e0, const float4& e1,
                                      const float4& e2, const float4& e3,
                                      short8& a0, short8& a1) {
  a0[0] = (short)f2bf(e0.x); a0[1] = (short)f2bf(e0.y);
  a0[2] = (short)f2bf(e0.z); a0[3] = (short)f2bf(e0.w);
  a0[4] = (short)f2bf(e1.x); a0[5] = (short)f2bf(e1.y);
  a0[6] = (short)f2bf(e1.z); a0[7] = (short)f2bf(e1.w);
  a1[0] = (short)f2bf(e2.x); a1[1] = (short)f2bf(e2.y);
  a1[2] = (short)f2bf(e2.z); a1[3] = (short)f2bf(e2.w);
  a1[4] = (short)f2bf(e3.x); a1[5] = (short)f2bf(e3.y);
  a1[6] = (short)f2bf(e3.z); a1[7] = (short)f2bf(e3.w);
}

__device__ __forceinline__ void rowmlp_row(const float* __restrict__ in,
                                           const float* __restrict__ W,
                                           const float* __restrict__ bias,
                                           float* __restrict__ out, int r, int lane) {
  float rv = in[r * 64 + lane];
  float acc = bias ? bias[lane] : 0.f;
#pragma unroll
  for (int k = 0; k < 64; k++) acc += __shfl(rv, k, 64) * W[k * 64 + lane];
  out[r * 64 + lane] = acc;
}

// Fused setup: zero accumulators, build Wt (bf16, n-major, 4 sections), c1, c2.
// Wt rows 0-63: W1_bot^T, 64-127: W2_bot^T, 128-191: W3_top^T, 192-255: W3_bot^T
__global__ __launch_bounds__(256) void k_prep(
    const float* __restrict__ ap_hid, const float* __restrict__ ue_hid,
    const float* __restrict__ W1, const float* __restrict__ b1,
    const float* __restrict__ W2, const float* __restrict__ b2,
    const float* __restrict__ W3, unsigned short* __restrict__ Wt,
    float* __restrict__ acc_zero, float* __restrict__ c1, float* __restrict__ c2) {
  int bx = blockIdx.x, tid = threadIdx.x;
  if (bx < 320) {
    int i = bx * 256 + tid;
    if (i < 81920) acc_zero[i] = 0.f;
  } else if (bx < 384) {
    int idx = (bx - 320) * 256 + tid;  // 16384 total
    int r = idx >> 6, k = idx & 63;
    int sec = r >> 6, d = r & 63;
    float v;
    if (sec == 0)      v = W1[(64 + k) * 64 + d];
    else if (sec == 1) v = W2[(64 + k) * 64 + d];
    else if (sec == 2) v = W3[k * 64 + d];
    else               v = W3[(64 + k) * 64 + d];
    Wt[r * 64 + k] = f2bf(v);
  } else if (bx < 448) {
    int r = (bx - 384) * 4 + (tid >> 6);
    rowmlp_row(ap_hid, W1, b1, c1, r, tid & 63);
  } else {  // bx in [448, 704)
    int r = (bx - 448) * 4 + (tid >> 6);
    rowmlp_row(ue_hid, W2, b2, c2, r, tid & 63);
  }
}

// Fused: s3 = ap_sum@W3b, s4 = ue_sum@W3b + b3
__global__ __launch_bounds__(256) void k_post(
    const float* __restrict__ ap_sum, const float* __restrict__ ue_sum,
    const float* __restrict__ W3, const float* __restrict__ b3,
    float* __restrict__ s3, float* __restrict__ s4) {
  int bx = blockIdx.x, tid = threadIdx.x;
  if (bx < 64) {
    int r = bx * 4 + (tid >> 6);
    rowmlp_row(ap_sum, W3 + 4096, nullptr, s3, r, tid & 63);
  } else {  // bx in [64, 320)
    int r = (bx - 64) * 4 + (tid >> 6);
    rowmlp_row(ue_sum, W3 + 4096, b3, s4, r, tid & 63);
  }
}

// Pass 1: ap_sum[a] = sum_u relu(edge@W1b + c1[a]); ue_sum[u] = sum_a relu(edge@W2b + c2[u]).
// 1024 blocks: 4 a-slices x one 64-u panel. A-fragments loaded directly from
// global (lane fr = u-row, fq = k-group); next slice prefetched into registers.
// No LDS, no barriers.
__global__ __launch_bounds__(256) void k_pass1(
    const float* __restrict__ edge, const unsigned short* __restrict__ Wt,
    const float* __restrict__ c1, const float* __restrict__ c2,
    float* __restrict__ ap_sum, float* __restrict__ ue_sum) {
  int tid = threadIdx.x, lane = tid & 63, w = tid >> 6;
  int fr = lane & 15, fq = lane >> 4;
  int a0 = (blockIdx.x >> 4) * 4;
  int u0 = (blockIdx.x & 15) * 64;
  int urow = u0 + w * 16 + fr;
  const float* erow = edge + urow * 64 + fq * 8;  // + a*65536

  // loop-invariant B-fragments: n-tiles 0-3 = W1b, 4-7 = W2b (held in regs)
  short8 bw[8][2];
#pragma unroll
  for (int nt = 0; nt < 8; nt++)
#pragma unroll
    for (int ks = 0; ks < 2; ks++)
      bw[nt][ks] = *(const short8*)(Wt + (nt * 16 + fr) * 64 + ks * 32 + fq * 8);

  float c2v[4][4];
#pragma unroll
  for (int j = 0; j < 4; j++)
#pragma unroll
    for (int i = 0; i < 4; i++)
      c2v[j][i] = c2[(u0 + w * 16 + fq * 4 + i) * 64 + j * 16 + fr];

  float ureg[4][4];
#pragma unroll
  for (int j = 0; j < 4; j++)
#pragma unroll
    for (int i = 0; i < 4; i++) ureg[j][i] = 0.f;

  // prefetch slice a0
  const float* p0 = erow + a0 * 65536;
  float4 e0 = *(const float4*)(p0);
  float4 e1 = *(const float4*)(p0 + 4);
  float4 e2 = *(const float4*)(p0 + 32);
  float4 e3 = *(const float4*)(p0 + 36);
  float c1v[4];
#pragma unroll
  for (int j = 0; j < 4; j++) c1v[j] = c1[a0 * 64 + j * 16 + fr];

  for (int c = 0; c < 4; c++) {
    int a = a0 + c;
    float4 n0, n1, n2, n3;
    float nc1[4];
    if (c < 3) {
      const float* np = erow + (a + 1) * 65536;
      n0 = *(const float4*)(np);
      n1 = *(const float4*)(np + 4);
      n2 = *(const float4*)(np + 32);
      n3 = *(const float4*)(np + 36);
#pragma unroll
      for (int j = 0; j < 4; j++) nc1[j] = c1[(a + 1) * 64 + j * 16 + fr];
    }
    short8 af0, af1;
    cvt16(e0, e1, e2, e3, af0, af1);

    // P1 -> reduce over the wave's 16 u-rows -> ap_sum[a]
#pragma unroll
    for (int j = 0; j < 4; j++) {
      f32x4 acc = {0.f, 0.f, 0.f, 0.f};
      acc = mfma16(af0, bw[j][0], acc);
      acc = mfma16(af1, bw[j][1], acc);
      float cv = c1v[j];
      float rs = fmaxf(acc[0] + cv, 0.f) + fmaxf(acc[1] + cv, 0.f) +
                 fmaxf(acc[2] + cv, 0.f) + fmaxf(acc[3] + cv, 0.f);
      rs += __shfl_xor(rs, 16, 64);
      rs += __shfl_xor(rs, 32, 64);
      if (lane < 16) atomicAdd(&ap_sum[a * 64 + j * 16 + lane], rs);
    }
    // P2 -> per-(u,d) register accumulation across the 4 a's
#pragma unroll
    for (int j = 0; j < 4; j++) {
      f32x4 acc = {0.f, 0.f, 0.f, 0.f};
      acc = mfma16(af0, bw[4 + j][0], acc);
      acc = mfma16(af1, bw[4 + j][1], acc);
#pragma unroll
      for (int i = 0; i < 4; i++)
        ureg[j][i] += fmaxf(acc[i] + c2v[j][i], 0.f);
    }
    if (c < 3) {
      e0 = n0; e1 = n1; e2 = n2; e3 = n3;
#pragma unroll
      for (int j = 0; j < 4; j++) c1v[j] = nc1[j];
    }
  }
#pragma unroll
  for (int j = 0; j < 4; j++)
#pragma unroll
    for (int i = 0; i < 4; i++)
      atomicAdd(&ue_sum[(u0 + w * 16 + fq * 4 + i) * 64 + j * 16 + fr], ureg[j][i]);
}

// Pass 2: out = P3 - t@W3b + s3[a] + s4[u], t = relu(P1+c1)+relu(P2+c2).
// 1024 blocks: one a x 4 u-panels. Edge A-frags direct from global with
// next-panel register prefetch; all weights in padded LDS (one barrier);
// t round-trips through wave-private LDS rows (no barrier).
__global__ __launch_bounds__(256) void k_pass2(
    const float* __restrict__ edge, const unsigned short* __restrict__ Wt,
    const float* __restrict__ c1, const float* __restrict__ c2,
    const float* __restrict__ s3, const float* __restrict__ s4,
    float* __restrict__ out) {
  __shared__ unsigned short W_lds[256 * 72];  // 4 sections x 64 rows, pad->72
  __shared__ unsigned short t_lds[64 * 72];
  int tid = threadIdx.x, lane = tid & 63, w = tid >> 6;
  int fr = lane & 15, fq = lane >> 4;
  int a = blockIdx.x >> 2;
  int ubase = (blockIdx.x & 3) * 256;

  // stage all weights into LDS (256 rows x 128B)
#pragma unroll
  for (int it = 0; it < 8; it++) {
    int r = it * 32 + (tid >> 3), seg = tid & 7;
    *(uint4*)&W_lds[r * 72 + seg * 8] = *(const uint4*)(Wt + r * 64 + seg * 8);
  }

  float c1v[4], s3v[4];
#pragma unroll
  for (int j = 0; j < 4; j++) {
    c1v[j] = c1[a * 64 + j * 16 + fr];
    s3v[j] = s3[a * 64 + j * 16 + fr];
  }

  // prefetch panel 0 edge
  const float* er0 = edge + (a * 1024 + ubase + w * 16 + fr) * 64 + fq * 8;
  float4 e0 = *(const float4*)(er0);
  float4 e1 = *(const float4*)(er0 + 4);
  float4 e2 = *(const float4*)(er0 + 32);
  float4 e3 = *(const float4*)(er0 + 36);

  __syncthreads();

  for (int pnl = 0; pnl < 4; pnl++) {
    int upan = ubase + pnl * 64;
    float4 n0, n1, n2, n3;
    if (pnl < 3) {
      const float* nr = edge + (a * 1024 + upan + 64 + w * 16 + fr) * 64 + fq * 8;
      n0 = *(const float4*)(nr);
      n1 = *(const float4*)(nr + 4);
      n2 = *(const float4*)(nr + 32);
      n3 = *(const float4*)(nr + 36);
    }
    float c2v[4][4], s4v[4][4];
#pragma unroll
    for (int j = 0; j < 4; j++)
#pragma unroll
      for (int i = 0; i < 4; i++) {
        int u = upan + w * 16 + fq * 4 + i;
        c2v[j][i] = c2[u * 64 + j * 16 + fr];
        s4v[j][i] = s4[u * 64 + j * 16 + fr];
      }
    short8 af0, af1;
    cvt16(e0, e1, e2, e3, af0, af1);

    f32x4 accP3[4];
#pragma unroll
    for (int j = 0; j < 4; j++) {
      const unsigned short* wr = &W_lds[(j * 16 + fr) * 72 + fq * 8];
      short8 b10 = *(const short8*)(wr);
      short8 b11 = *(const short8*)(wr + 32);
      short8 b20 = *(const short8*)(wr + 64 * 72);
      short8 b21 = *(const short8*)(wr + 64 * 72 + 32);
      short8 b30 = *(const short8*)(wr + 128 * 72);
      short8 b31 = *(const short8*)(wr + 128 * 72 + 32);
      f32x4 a1 = {0.f, 0.f, 0.f, 0.f};
      a1 = mfma16(af0, b10, a1);
      a1 = mfma16(af1, b11, a1);
      f32x4 a2 = {0.f, 0.f, 0.f, 0.f};
      a2 = mfma16(af0, b20, a2);
      a2 = mfma16(af1, b21, a2);
      f32x4 p3 = {0.f, 0.f, 0.f, 0.f};
      p3 = mfma16(af0, b30, p3);
      p3 = mfma16(af1, b31, p3);
      accP3[j] = p3;
#pragma unroll
      for (int i = 0; i < 4; i++) {
        float tv = fmaxf(a1[i] + c1v[j], 0.f) + fmaxf(a2[i] + c2v[j][i], 0.f);
        t_lds[(w * 16 + fq * 4 + i) * 72 + j * 16 + fr] = f2bf(tv);  // wave-private
      }
    }
    // GEMM2: A = t (this wave's own rows; DS in-order per wave, no barrier)
    short8 tf0 = *(const short8*)&t_lds[(w * 16 + fr) * 72 + fq * 8];
    short8 tf1 = *(const short8*)&t_lds[(w * 16 + fr) * 72 + 32 + fq * 8];
#pragma unroll
    for (int j = 0; j < 4; j++) {
      const unsigned short* wr = &W_lds[(192 + j * 16 + fr) * 72 + fq * 8];
      short8 b0 = *(const short8*)(wr);
      short8 b1 = *(const short8*)(wr + 32);
      f32x4 acc = {0.f, 0.f, 0.f, 0.f};
      acc = mfma16(tf0, b0, acc);
      acc = mfma16(tf1, b1, acc);
#pragma unroll
      for (int i = 0; i < 4; i++) {
        int u = upan + w * 16 + fq * 4 + i;
        out[(a * 1024 + u) * 64 + j * 16 + fr] =
            accP3[j][i] - acc[i] + s3v[j] + s4v[j][i];
      }
    }
    if (pnl < 3) { e0 = n0; e1 = n1; e2 = n2; e3 = n3; }
  }
}

extern "C" void kernel_launch(void* const* d_in, const int* in_sizes, int n_in,
                              void* d_out, int out_size, void* d_ws, size_t ws_size,
                              hipStream_t stream) {
  const float* ap_hid = (const float*)d_in[0];
  const float* ue_hid = (const float*)d_in[1];
  const float* edge   = (const float*)d_in[2];
  const float* W1     = (const float*)d_in[3];
  const float* b1     = (const float*)d_in[4];
  const float* W2     = (const float*)d_in[5];
  const float* b2     = (const float*)d_in[6];
  const float* W3     = (const float*)d_in[7];
  const float* b3     = (const float*)d_in[8];
  float* out = (float*)d_out;

  char* ws = (char*)d_ws;
  unsigned short* Wt = (unsigned short*)ws;          //  32768 B
  float* c1     = (float*)(ws + 32768);              //  65536 B
  float* c2     = (float*)(ws + 98304);              // 262144 B
  float* ap_sum = (float*)(ws + 360448);             //  65536 B
  float* ue_sum = (float*)(ws + 425984);             // 262144 B
  float* s3     = (float*)(ws + 688128);             //  65536 B
  float* s4     = (float*)(ws + 753664);             // 262144 B

  k_prep<<<704, 256, 0, stream>>>(ap_hid, ue_hid, W1, b1, W2, b2, W3, Wt,
                                  (float*)(ws + 360448), c1, c2);
  k_pass1<<<1024, 256, 0, stream>>>(edge, Wt, c1, c2, ap_sum, ue_sum);
  k_post<<<320, 256, 0, stream>>>(ap_sum, ue_sum, W3, b3, s3, s4);
  k_pass2<<<1024, 256, 0, stream>>>(edge, Wt, c1, c2, s3, s4, out);
}